// Round 1
// baseline (560.380 us; speedup 1.0000x reference)
//
#include <hip/hip_runtime.h>

#define N_NODES 131072
#define N_EDGES 1048576
#define N_GRAPHS 1024
#define EMB 96
#define HID 64
#define CAP 64   // max in-degree stored; Poisson(8) => P(deg>=64) ~ 1e-40

// h = x @ W  (per-row), plus a_s = h.att_src, a_d = h.att_dst
// block: 256 threads = 4 waves; wave handles one row, lane = output column.
__global__ __launch_bounds__(256) void k_linear(const float* __restrict__ x,
    const float* __restrict__ W, const float* __restrict__ att_src,
    const float* __restrict__ att_dst, float* __restrict__ h,
    float* __restrict__ a_s, float* __restrict__ a_d)
{
    __shared__ float Wl[EMB * HID];   // 24.6 KB
    __shared__ float xs[4][EMB];      // 1.5 KB
    int tid = threadIdx.x;
    int c = tid & 63;
    int ty = tid >> 6;
    int row = blockIdx.x * 4 + ty;
    for (int t = tid; t < EMB * HID; t += 256) Wl[t] = W[t];
    for (int k = c; k < EMB; k += 64) xs[ty][k] = x[row * EMB + k];
    __syncthreads();
    float acc = 0.f;
    #pragma unroll
    for (int k = 0; k < EMB; ++k) acc += xs[ty][k] * Wl[k * HID + c];
    h[row * HID + c] = acc;
    float s1 = acc * att_src[c];
    float s2 = acc * att_dst[c];
    #pragma unroll
    for (int off = 32; off >= 1; off >>= 1) {
        s1 += __shfl_xor(s1, off, 64);
        s2 += __shfl_xor(s2, off, 64);
    }
    if (c == 0) { a_s[row] = s1; a_d[row] = s2; }
}

// Build fixed-capacity CSR grouped by dst.
__global__ __launch_bounds__(256) void k_build(const int* __restrict__ src,
    const int* __restrict__ dst, int* __restrict__ cnt, int* __restrict__ slots)
{
    int e = blockIdx.x * 256 + threadIdx.x;
    if (e < N_EDGES) {
        int d = dst[e];
        int slot = atomicAdd(&cnt[d], 1);
        if (slot < CAP) slots[d * CAP + slot] = src[e];
    }
}

// One wave per node: fused softmax-weighted aggregation + bias + pooled atomic add.
__global__ __launch_bounds__(256) void k_accum(const float* __restrict__ h,
    const float* __restrict__ a_s, const float* __restrict__ a_d,
    const int* __restrict__ cnt, const int* __restrict__ slots,
    const float* __restrict__ bias, const int* __restrict__ batch,
    float* __restrict__ pool, float* __restrict__ gcnt)
{
    int tid = threadIdx.x;
    int lane = tid & 63;
    int node = blockIdx.x * 4 + (tid >> 6);
    float adi = a_d[node];
    float asi = a_s[node];
    int deg = cnt[node]; if (deg > CAP) deg = CAP;
    // self-loop term
    float t0 = asi + adi;
    t0 = t0 > 0.f ? t0 : 0.2f * t0;
    float w = __expf(t0);
    float z = w;
    float acc = w * h[node * HID + lane];
    const int* sl = slots + node * CAP;
    for (int j = 0; j < deg; ++j) {
        int s = sl[j];                       // wave-broadcast read
        float t = a_s[s] + adi;              // wave-broadcast read
        t = t > 0.f ? t : 0.2f * t;
        float wj = __expf(t);
        z += wj;
        acc += wj * h[s * HID + lane];       // coalesced 256B gather
    }
    float outv = acc / (z + 1e-16f) + bias[lane];
    int g = batch[node];
    atomicAdd(&pool[g * HID + lane], outv);
    if (lane == 0) atomicAdd(&gcnt[g], 1.0f);
}

// Per-graph mean, FC (64 -> 3), log_softmax. One wave per graph.
__global__ __launch_bounds__(256) void k_head(const float* __restrict__ pool,
    const float* __restrict__ gcnt, const float* __restrict__ fc_w,
    const float* __restrict__ fc_b, float* __restrict__ out)
{
    int tid = threadIdx.x;
    int lane = tid & 63;
    int g = blockIdx.x * 4 + (tid >> 6);
    float p = pool[g * HID + lane] / fmaxf(gcnt[g], 1.0f);
    float l0 = p * fc_w[0 * HID + lane];
    float l1 = p * fc_w[1 * HID + lane];
    float l2 = p * fc_w[2 * HID + lane];
    #pragma unroll
    for (int off = 32; off >= 1; off >>= 1) {
        l0 += __shfl_xor(l0, off, 64);
        l1 += __shfl_xor(l1, off, 64);
        l2 += __shfl_xor(l2, off, 64);
    }
    l0 += fc_b[0]; l1 += fc_b[1]; l2 += fc_b[2];
    float m = fmaxf(l0, fmaxf(l1, l2));
    float lse = m + logf(__expf(l0 - m) + __expf(l1 - m) + __expf(l2 - m));
    if (lane == 0) {
        out[g * 3 + 0] = l0 - lse;
        out[g * 3 + 1] = l1 - lse;
        out[g * 3 + 2] = l2 - lse;
    }
}

extern "C" void kernel_launch(void* const* d_in, const int* in_sizes, int n_in,
                              void* d_out, int out_size, void* d_ws, size_t ws_size,
                              hipStream_t stream)
{
    const float* x        = (const float*)d_in[0];
    const int*   ei       = (const int*)d_in[1];   // [2, E] int32
    const int*   batch    = (const int*)d_in[2];
    const float* W        = (const float*)d_in[3];
    const float* att_src  = (const float*)d_in[4];
    const float* att_dst  = (const float*)d_in[5];
    const float* bias_gat = (const float*)d_in[6];
    const float* fc_w     = (const float*)d_in[7];
    const float* fc_b     = (const float*)d_in[8];
    float* out = (float*)d_out;

    char* ws = (char*)d_ws;
    size_t off = 0;
    auto alloc = [&](size_t bytes) {
        void* p = ws + off;
        off += (bytes + 255) & ~(size_t)255;
        return p;
    };
    float* h     = (float*)alloc((size_t)N_NODES * HID * 4);   // 33.5 MB
    int*   slots = (int*)  alloc((size_t)N_NODES * CAP * 4);   // 33.5 MB
    float* a_s   = (float*)alloc((size_t)N_NODES * 4);
    float* a_d   = (float*)alloc((size_t)N_NODES * 4);
    int*   cnt   = (int*)  alloc((size_t)N_NODES * 4);
    float* pool  = (float*)alloc((size_t)N_GRAPHS * HID * 4);
    float* gcnt  = (float*)alloc((size_t)N_GRAPHS * 4);

    hipMemsetAsync(cnt, 0, (size_t)N_NODES * 4, stream);
    hipMemsetAsync(pool, 0, (size_t)N_GRAPHS * HID * 4, stream);
    hipMemsetAsync(gcnt, 0, (size_t)N_GRAPHS * 4, stream);

    k_linear<<<N_NODES / 4, 256, 0, stream>>>(x, W, att_src, att_dst, h, a_s, a_d);
    k_build<<<N_EDGES / 256, 256, 0, stream>>>(ei, ei + N_EDGES, cnt, slots);
    k_accum<<<N_NODES / 4, 256, 0, stream>>>(h, a_s, a_d, cnt, slots, bias_gat,
                                             batch, pool, gcnt);
    k_head<<<N_GRAPHS / 4, 256, 0, stream>>>(pool, gcnt, fc_w, fc_b, out);
}